// Round 13
// baseline (106.347 us; speedup 1.0000x reference)
//
#include <hip/hip_runtime.h>
#include <hip/hip_bf16.h>
#include <cstdint>
#include <cstddef>

#define NB 2048
#define NT 200
#define ND 64
#define NH1 128
#define NH2 64
#define NT2 13   // 13 tiles of 16 rows = 208 >= 200

typedef __bf16 bf16x8 __attribute__((ext_vector_type(8)));
typedef float f32x4 __attribute__((ext_vector_type(4)));

#define MFMA16(A, Bv, C) __builtin_amdgcn_mfma_f32_16x16x32_bf16((A), (Bv), (C), 0, 0, 0)

union BF8u { __bf16 b[8]; bf16x8 v; uint4 u4; };
union BF4u { __bf16 b[4]; uint2 u2; };

// prep: QpT[j][c] = (W1q+W1d)^T; AbT[j][c] = (W1k-W1d)^T; PT[j][c] = W1prod^T;
//       W2t[h2][j] = bf16(W2[j][h2])
__global__ void prep_kernel(const float* __restrict__ W1, const float* __restrict__ W2,
                            float* __restrict__ QpT, float* __restrict__ AbT,
                            float* __restrict__ PT, __bf16* __restrict__ W2t) {
    int tid = blockIdx.x * blockDim.x + threadIdx.x;
    if (tid < NH1 * ND) {
        int jj = tid >> 6, cc = tid & 63;
        QpT[tid] = W1[cc * NH1 + jj] + W1[(128 + cc) * NH1 + jj];
        AbT[tid] = W1[(64 + cc) * NH1 + jj] - W1[(128 + cc) * NH1 + jj];
        PT[tid]  = W1[(192 + cc) * NH1 + jj];
        int j2 = tid >> 7, k = tid & 127;
        W2t[tid] = (__bf16)W2[k * NH2 + j2];
    }
}

// ONE WAVE PER BATCH ROW. No s_barrier anywhere: LDS is wave-private, and
// same-wave ds_write -> ds_read ordering is enforced by compiler lgkmcnt.
// LDS (9856 B/block): H1[2][16][136] bf16 (8704) + QH[128] f32 (512)
//                     + B2WO[128] f32 (512) + EB[2][16] f32 (128)
__global__ __launch_bounds__(64, 2)
void attn_main(const float* __restrict__ query, const float* __restrict__ key,
               const float* __restrict__ value, const int* __restrict__ mask,
               const float* __restrict__ b1, const float* __restrict__ b2,
               const float* __restrict__ Wo,
               const float* __restrict__ QpT, const float* __restrict__ AbT,
               const float* __restrict__ PT, const __bf16* __restrict__ W2t,
               float* __restrict__ out)
{
    __shared__ __align__(16) char smem[9856];
    auto H1 = (__bf16(*)[16][136])(smem);          // [2][16][136]
    float* QH   = (float*)(smem + 8704);           // qh[128]
    float* B2WO = (float*)(smem + 9216);           // b2[64] ++ Wo[64]
    auto EB = (float(*)[16])(smem + 9728);         // e broadcast, double-buffered

    const int b = blockIdx.x;
    const int lane = threadIdx.x;
    const int jn = lane & 15;
    const int g4 = lane >> 4;
    const int g8 = g4 * 8;

    const float* kb = key + (size_t)b * NT * ND;
    const float* vb = value + (size_t)b * NT * ND;

    // ---- k tile 0 prefetch (B-frag gather: lane reads k[t=jn][c=32kk+g8+e]) ----
    float4 pf0, pf1, pf2, pf3;
    {
        const float* p = kb + jn * ND + g8;
        pf0 = *(const float4*)(p);
        pf1 = *(const float4*)(p + 4);
        pf2 = *(const float4*)(p + 32);
        pf3 = *(const float4*)(p + 36);
    }

    // ---- q values (c = 32kk + g8 + e), jn-independent -> column-replicated ----
    const float* qp = query + (size_t)b * ND;
    const float4 qa0 = *(const float4*)(qp + g8);
    const float4 qa1 = *(const float4*)(qp + g8 + 4);
    const float4 qb0 = *(const float4*)(qp + 32 + g8);
    const float4 qb1 = *(const float4*)(qp + 32 + g8 + 4);
    bf16x8 qfrag0, qfrag1;
    {
        BF8u u;
        u.b[0]=(__bf16)qa0.x; u.b[1]=(__bf16)qa0.y; u.b[2]=(__bf16)qa0.z; u.b[3]=(__bf16)qa0.w;
        u.b[4]=(__bf16)qa1.x; u.b[5]=(__bf16)qa1.y; u.b[6]=(__bf16)qa1.z; u.b[7]=(__bf16)qa1.w;
        qfrag0 = u.v;
        u.b[0]=(__bf16)qb0.x; u.b[1]=(__bf16)qb0.y; u.b[2]=(__bf16)qb0.z; u.b[3]=(__bf16)qb0.w;
        u.b[4]=(__bf16)qb1.x; u.b[5]=(__bf16)qb1.y; u.b[6]=(__bf16)qb1.z; u.b[7]=(__bf16)qb1.w;
        qfrag1 = u.v;
    }

    // ---- W2^T A-fragments, all held in registers (16 frags) ----
    bf16x8 w2f[4][4];
    #pragma unroll
    for (int ht = 0; ht < 4; ++ht)
        #pragma unroll
        for (int kk = 0; kk < 4; ++kk)
            w2f[ht][kk] = *(const bf16x8*)(W2t + (16 * ht + jn) * NH1 + 32 * kk + g8);

    // ---- qh via prologue MFMA: C[j][t] = (QpT @ q_replicated)[j] = qh0[j] ----
    #pragma unroll
    for (int n = 0; n < 8; ++n) {
        bf16x8 qpt0, qpt1;
        {
            const float* p = QpT + (16 * n + jn) * ND + g8;
            const float4 a0 = *(const float4*)(p);
            const float4 a1 = *(const float4*)(p + 4);
            const float4 a2 = *(const float4*)(p + 32);
            const float4 a3 = *(const float4*)(p + 36);
            BF8u u;
            u.b[0]=(__bf16)a0.x; u.b[1]=(__bf16)a0.y; u.b[2]=(__bf16)a0.z; u.b[3]=(__bf16)a0.w;
            u.b[4]=(__bf16)a1.x; u.b[5]=(__bf16)a1.y; u.b[6]=(__bf16)a1.z; u.b[7]=(__bf16)a1.w;
            qpt0 = u.v;
            u.b[0]=(__bf16)a2.x; u.b[1]=(__bf16)a2.y; u.b[2]=(__bf16)a2.z; u.b[3]=(__bf16)a2.w;
            u.b[4]=(__bf16)a3.x; u.b[5]=(__bf16)a3.y; u.b[6]=(__bf16)a3.z; u.b[7]=(__bf16)a3.w;
            qpt1 = u.v;
        }
        f32x4 aq = {0.f, 0.f, 0.f, 0.f};
        aq = MFMA16(qpt0, qfrag0, aq);
        aq = MFMA16(qpt1, qfrag1, aq);
        const float4 b1v = *(const float4*)(b1 + 16 * n + 4 * g4);
        if (jn == 0) {
            float4 qv{aq[0] + b1v.x, aq[1] + b1v.y, aq[2] + b1v.z, aq[3] + b1v.w};
            *(float4*)(QH + 16 * n + 4 * g4) = qv;
        }
    }

    // ---- stage b2 / Wo into LDS ----
    B2WO[lane] = b2[lane];
    B2WO[64 + lane] = Wo[lane];

    // ---- GEMM1 A-frags: B_b^T[j][c] = AbT + q[c]*PT, all 16 held ----
    bf16x8 g1_b[8][2];
    #pragma unroll
    for (int n = 0; n < 8; ++n) {
        #pragma unroll
        for (int kk = 0; kk < 2; ++kk) {
            const float* ab = AbT + (16 * n + jn) * ND + 32 * kk + g8;
            const float* pt = PT  + (16 * n + jn) * ND + 32 * kk + g8;
            const float4 a0 = *(const float4*)(ab);
            const float4 a1 = *(const float4*)(ab + 4);
            const float4 p0 = *(const float4*)(pt);
            const float4 p1 = *(const float4*)(pt + 4);
            const float qv[8] = {
                kk ? qb0.x : qa0.x, kk ? qb0.y : qa0.y, kk ? qb0.z : qa0.z, kk ? qb0.w : qa0.w,
                kk ? qb1.x : qa1.x, kk ? qb1.y : qa1.y, kk ? qb1.z : qa1.z, kk ? qb1.w : qa1.w};
            const float av[8] = {a0.x,a0.y,a0.z,a0.w,a1.x,a1.y,a1.z,a1.w};
            const float pv[8] = {p0.x,p0.y,p0.z,p0.w,p1.x,p1.y,p1.z,p1.w};
            BF8u vh;
            #pragma unroll
            for (int e = 0; e < 8; ++e)
                vh.b[e] = (__bf16)fmaf(qv[e], pv[e], av[e]);
            g1_b[n][kk] = vh.v;
        }
    }

    // ---- main loop: 13 tiles of 16 t-rows, fully unrolled, ZERO barriers ----
    float O0 = 0.f, O1 = 0.f, O2 = 0.f, O3 = 0.f, den = 0.f;
    #pragma unroll
    for (int ti = 0; ti < NT2; ++ti) {
        const int t0 = ti * 16;
        const int buf = ti & 1;

        // convert current k tile to B-frags
        bf16x8 kf0, kf1;
        {
            BF8u u;
            u.b[0]=(__bf16)pf0.x; u.b[1]=(__bf16)pf0.y; u.b[2]=(__bf16)pf0.z; u.b[3]=(__bf16)pf0.w;
            u.b[4]=(__bf16)pf1.x; u.b[5]=(__bf16)pf1.y; u.b[6]=(__bf16)pf1.z; u.b[7]=(__bf16)pf1.w;
            kf0 = u.v;
            u.b[0]=(__bf16)pf2.x; u.b[1]=(__bf16)pf2.y; u.b[2]=(__bf16)pf2.z; u.b[3]=(__bf16)pf2.w;
            u.b[4]=(__bf16)pf3.x; u.b[5]=(__bf16)pf3.y; u.b[6]=(__bf16)pf3.z; u.b[7]=(__bf16)pf3.w;
            kf1 = u.v;
        }
        // issue next k tile (lands under this tile's compute)
        if (ti + 1 < NT2) {
            int t = t0 + 16 + jn;
            t = t < NT ? t : NT - 1;
            const float* p = kb + (size_t)t * ND + g8;
            pf0 = *(const float4*)(p);
            pf1 = *(const float4*)(p + 4);
            pf2 = *(const float4*)(p + 32);
            pf3 = *(const float4*)(p + 36);
        }

        // GEMM1: h1^T(ti) = B_b^T @ k^T  -> relu(+qh) -> H1[buf]
        #pragma unroll
        for (int n = 0; n < 8; ++n) {
            f32x4 ac = {0.f, 0.f, 0.f, 0.f};
            ac = MFMA16(g1_b[n][0], kf0, ac);
            ac = MFMA16(g1_b[n][1], kf1, ac);
            const float4 qv = *(const float4*)(QH + 16 * n + 4 * g4);
            BF4u pk;
            pk.b[0] = (__bf16)fmaxf(ac[0] + qv.x, 0.f);
            pk.b[1] = (__bf16)fmaxf(ac[1] + qv.y, 0.f);
            pk.b[2] = (__bf16)fmaxf(ac[2] + qv.z, 0.f);
            pk.b[3] = (__bf16)fmaxf(ac[3] + qv.w, 0.f);
            *(uint2*)(&H1[buf][jn][16 * n + 4 * g4]) = pk.u2;
        }

        // GEMM2: C2[h2][t] = W2^T @ h1  (h1 B-frags from wave-private LDS)
        bf16x8 hf[4];
        #pragma unroll
        for (int kk = 0; kk < 4; ++kk)
            hf[kk] = *(const bf16x8*)(&H1[buf][jn][32 * kk + g8]);
        f32x4 a2[4];
        #pragma unroll
        for (int ht = 0; ht < 4; ++ht) {
            f32x4 ac = {0.f, 0.f, 0.f, 0.f};
            ac = MFMA16(w2f[ht][0], hf[0], ac);
            ac = MFMA16(w2f[ht][1], hf[1], ac);
            ac = MFMA16(w2f[ht][2], hf[2], ac);
            ac = MFMA16(w2f[ht][3], hf[3], ac);
            a2[ht] = ac;
        }

        // score s[t=jn] = sum_h2 relu(C2 + b2) * Wo ; reduce over g4-lanes
        float sp = 0.f;
        #pragma unroll
        for (int ht = 0; ht < 4; ++ht) {
            const float4 bv = *(const float4*)(B2WO + 16 * ht + 4 * g4);
            const float4 wv = *(const float4*)(B2WO + 64 + 16 * ht + 4 * g4);
            sp += fmaxf(a2[ht][0] + bv.x, 0.f) * wv.x;
            sp += fmaxf(a2[ht][1] + bv.y, 0.f) * wv.y;
            sp += fmaxf(a2[ht][2] + bv.z, 0.f) * wv.z;
            sp += fmaxf(a2[ht][3] + bv.w, 0.f) * wv.w;
        }
        sp += __shfl_xor(sp, 16);
        sp += __shfl_xor(sp, 32);

        const int t = t0 + jn;
        const int mkv = mask[(size_t)b * NT + (t < NT ? t : NT - 1)];
        const float e = (t < NT && mkv != 0) ? __expf(sp) : 0.f;
        den += e;
        if (lane < 16) EB[buf][jn] = e;

        // V accumulate: lane (jn,g4) owns d = 4*jn..+4, t-rows t0 + 4*g4 + u
        #pragma unroll
        for (int u = 0; u < 4; ++u) {
            const float ev = EB[buf][4 * g4 + u];
            int tv = t0 + 4 * g4 + u;
            tv = tv < NT ? tv : NT - 1;
            const float4 vv = *(const float4*)(vb + (size_t)tv * ND + 4 * jn);
            O0 = fmaf(ev, vv.x, O0);
            O1 = fmaf(ev, vv.y, O1);
            O2 = fmaf(ev, vv.z, O2);
            O3 = fmaf(ev, vv.w, O3);
        }
    }

    // ---- final reduces (wave-local) + store ----
    O0 += __shfl_xor(O0, 16); O0 += __shfl_xor(O0, 32);
    O1 += __shfl_xor(O1, 16); O1 += __shfl_xor(O1, 32);
    O2 += __shfl_xor(O2, 16); O2 += __shfl_xor(O2, 32);
    O3 += __shfl_xor(O3, 16); O3 += __shfl_xor(O3, 32);
    den += __shfl_xor(den, 1);
    den += __shfl_xor(den, 2);
    den += __shfl_xor(den, 4);
    den += __shfl_xor(den, 8);
    if (lane < 16) {
        const float inv = 1.f / den;
        float4 o{O0 * inv, O1 * inv, O2 * inv, O3 * inv};
        *(float4*)(out + (size_t)b * ND + 4 * jn) = o;
    }
}

extern "C" void kernel_launch(void* const* d_in, const int* in_sizes, int n_in,
                              void* d_out, int out_size, void* d_ws, size_t ws_size,
                              hipStream_t stream) {
    const float* query = (const float*)d_in[0];
    const float* key   = (const float*)d_in[1];
    const float* value = (const float*)d_in[2];
    const int*   maskp = (const int*)d_in[3];
    const float* W1    = (const float*)d_in[4];
    const float* b1    = (const float*)d_in[5];
    const float* W2    = (const float*)d_in[6];
    const float* b2    = (const float*)d_in[7];
    const float* Wo    = (const float*)d_in[8];
    float* out = (float*)d_out;

    float* QpT = (float*)d_ws;                 // 128*64 f32
    float* AbT = QpT + NH1 * ND;               // 128*64 f32
    float* PT  = AbT + NH1 * ND;               // 128*64 f32
    __bf16* W2t = (__bf16*)(PT + NH1 * ND);    // 64*128 bf16

    prep_kernel<<<32, 256, 0, stream>>>(W1, W2, QpT, AbT, PT, W2t);
    attn_main<<<NB, 64, 0, stream>>>(query, key, value, maskp, b1, b2, Wo,
                                     QpT, AbT, PT, W2t, out);
}

// Round 14
// 76.346 us; speedup vs baseline: 1.3930x; 1.3930x over previous
//
#include <hip/hip_runtime.h>
#include <hip/hip_bf16.h>
#include <cstdint>
#include <cstddef>

#define NB 2048
#define NT 200
#define ND 64
#define NH1 128
#define NH2 64
#define NT2 13   // 13 tiles of 16 rows = 208 >= 200

typedef __bf16 bf16x8 __attribute__((ext_vector_type(8)));
typedef float f32x4 __attribute__((ext_vector_type(4)));

#define MFMA16(A, Bv, C) __builtin_amdgcn_mfma_f32_16x16x32_bf16((A), (Bv), (C), 0, 0, 0)

union BF8u { __bf16 b[8]; bf16x8 v; uint4 u4; };
union BF4u { __bf16 b[4]; uint2 u2; };

// prep: QpT[j][c] = (W1q+W1d)^T; AbT[j][c] = (W1k-W1d)^T; PT[j][c] = W1prod^T;
//       W2t[h2][j] = bf16(W2[j][h2])
__global__ void prep_kernel(const float* __restrict__ W1, const float* __restrict__ W2,
                            float* __restrict__ QpT, float* __restrict__ AbT,
                            float* __restrict__ PT, __bf16* __restrict__ W2t) {
    int tid = blockIdx.x * blockDim.x + threadIdx.x;
    if (tid < NH1 * ND) {
        int jj = tid >> 6, cc = tid & 63;
        QpT[tid] = W1[cc * NH1 + jj] + W1[(128 + cc) * NH1 + jj];
        AbT[tid] = W1[(64 + cc) * NH1 + jj] - W1[(128 + cc) * NH1 + jj];
        PT[tid]  = W1[(192 + cc) * NH1 + jj];
        int j2 = tid >> 7, k = tid & 127;
        W2t[tid] = (__bf16)W2[k * NH2 + j2];
    }
}

// ONE WAVE PER BATCH ROW. No s_barrier anywhere: LDS is wave-private, and
// same-wave ds_write -> ds_read ordering is enforced by compiler lgkmcnt.
// __launch_bounds__(64,1): 256-VGPR budget. Grid = 2048 waves = 2 waves/SIMD,
// which the HW permits at VGPR<=256 -- raising the budget costs no occupancy.
// LDS (9856 B/block): H1[2][16][136] bf16 (8704) + QH[128] f32 (512)
//                     + B2WO[128] f32 (512) + EB[2][16] f32 (128)
__global__ __launch_bounds__(64, 1)
void attn_main(const float* __restrict__ query, const float* __restrict__ key,
               const float* __restrict__ value, const int* __restrict__ mask,
               const float* __restrict__ b1, const float* __restrict__ b2,
               const float* __restrict__ Wo,
               const float* __restrict__ QpT, const float* __restrict__ AbT,
               const float* __restrict__ PT, const __bf16* __restrict__ W2t,
               float* __restrict__ out)
{
    __shared__ __align__(16) char smem[9856];
    auto H1 = (__bf16(*)[16][136])(smem);          // [2][16][136]
    float* QH   = (float*)(smem + 8704);           // qh[128]
    float* B2WO = (float*)(smem + 9216);           // b2[64] ++ Wo[64]
    auto EB = (float(*)[16])(smem + 9728);         // e broadcast, double-buffered

    const int b = blockIdx.x;
    const int lane = threadIdx.x;
    const int jn = lane & 15;
    const int g4 = lane >> 4;
    const int g8 = g4 * 8;

    const float* kb = key + (size_t)b * NT * ND;
    const float* vb = value + (size_t)b * NT * ND;

    // ---- k tile 0 prefetch (B-frag gather: lane reads k[t=jn][c=32kk+g8+e]) ----
    float4 pf0, pf1, pf2, pf3;
    {
        const float* p = kb + jn * ND + g8;
        pf0 = *(const float4*)(p);
        pf1 = *(const float4*)(p + 4);
        pf2 = *(const float4*)(p + 32);
        pf3 = *(const float4*)(p + 36);
    }

    // ---- q values (c = 32kk + g8 + e), jn-independent -> column-replicated ----
    const float* qp = query + (size_t)b * ND;
    const float4 qa0 = *(const float4*)(qp + g8);
    const float4 qa1 = *(const float4*)(qp + g8 + 4);
    const float4 qb0 = *(const float4*)(qp + 32 + g8);
    const float4 qb1 = *(const float4*)(qp + 32 + g8 + 4);
    bf16x8 qfrag0, qfrag1;
    {
        BF8u u;
        u.b[0]=(__bf16)qa0.x; u.b[1]=(__bf16)qa0.y; u.b[2]=(__bf16)qa0.z; u.b[3]=(__bf16)qa0.w;
        u.b[4]=(__bf16)qa1.x; u.b[5]=(__bf16)qa1.y; u.b[6]=(__bf16)qa1.z; u.b[7]=(__bf16)qa1.w;
        qfrag0 = u.v;
        u.b[0]=(__bf16)qb0.x; u.b[1]=(__bf16)qb0.y; u.b[2]=(__bf16)qb0.z; u.b[3]=(__bf16)qb0.w;
        u.b[4]=(__bf16)qb1.x; u.b[5]=(__bf16)qb1.y; u.b[6]=(__bf16)qb1.z; u.b[7]=(__bf16)qb1.w;
        qfrag1 = u.v;
    }

    // ---- W2^T A-fragments, all held in registers (16 frags) ----
    bf16x8 w2f[4][4];
    #pragma unroll
    for (int ht = 0; ht < 4; ++ht)
        #pragma unroll
        for (int kk = 0; kk < 4; ++kk)
            w2f[ht][kk] = *(const bf16x8*)(W2t + (16 * ht + jn) * NH1 + 32 * kk + g8);

    // ---- qh via prologue MFMA: C[j][t] = (QpT @ q_replicated)[j] = qh0[j] ----
    #pragma unroll
    for (int n = 0; n < 8; ++n) {
        bf16x8 qpt0, qpt1;
        {
            const float* p = QpT + (16 * n + jn) * ND + g8;
            const float4 a0 = *(const float4*)(p);
            const float4 a1 = *(const float4*)(p + 4);
            const float4 a2 = *(const float4*)(p + 32);
            const float4 a3 = *(const float4*)(p + 36);
            BF8u u;
            u.b[0]=(__bf16)a0.x; u.b[1]=(__bf16)a0.y; u.b[2]=(__bf16)a0.z; u.b[3]=(__bf16)a0.w;
            u.b[4]=(__bf16)a1.x; u.b[5]=(__bf16)a1.y; u.b[6]=(__bf16)a1.z; u.b[7]=(__bf16)a1.w;
            qpt0 = u.v;
            u.b[0]=(__bf16)a2.x; u.b[1]=(__bf16)a2.y; u.b[2]=(__bf16)a2.z; u.b[3]=(__bf16)a2.w;
            u.b[4]=(__bf16)a3.x; u.b[5]=(__bf16)a3.y; u.b[6]=(__bf16)a3.z; u.b[7]=(__bf16)a3.w;
            qpt1 = u.v;
        }
        f32x4 aq = {0.f, 0.f, 0.f, 0.f};
        aq = MFMA16(qpt0, qfrag0, aq);
        aq = MFMA16(qpt1, qfrag1, aq);
        const float4 b1v = *(const float4*)(b1 + 16 * n + 4 * g4);
        if (jn == 0) {
            float4 qv{aq[0] + b1v.x, aq[1] + b1v.y, aq[2] + b1v.z, aq[3] + b1v.w};
            *(float4*)(QH + 16 * n + 4 * g4) = qv;
        }
    }

    // ---- stage b2 / Wo into LDS ----
    B2WO[lane] = b2[lane];
    B2WO[64 + lane] = Wo[lane];

    // ---- GEMM1 A-frags: B_b^T[j][c] = AbT + q[c]*PT, all 16 held ----
    bf16x8 g1_b[8][2];
    #pragma unroll
    for (int n = 0; n < 8; ++n) {
        #pragma unroll
        for (int kk = 0; kk < 2; ++kk) {
            const float* ab = AbT + (16 * n + jn) * ND + 32 * kk + g8;
            const float* pt = PT  + (16 * n + jn) * ND + 32 * kk + g8;
            const float4 a0 = *(const float4*)(ab);
            const float4 a1 = *(const float4*)(ab + 4);
            const float4 p0 = *(const float4*)(pt);
            const float4 p1 = *(const float4*)(pt + 4);
            const float qv[8] = {
                kk ? qb0.x : qa0.x, kk ? qb0.y : qa0.y, kk ? qb0.z : qa0.z, kk ? qb0.w : qa0.w,
                kk ? qb1.x : qa1.x, kk ? qb1.y : qa1.y, kk ? qb1.z : qa1.z, kk ? qb1.w : qa1.w};
            const float av[8] = {a0.x,a0.y,a0.z,a0.w,a1.x,a1.y,a1.z,a1.w};
            const float pv[8] = {p0.x,p0.y,p0.z,p0.w,p1.x,p1.y,p1.z,p1.w};
            BF8u vh;
            #pragma unroll
            for (int e = 0; e < 8; ++e)
                vh.b[e] = (__bf16)fmaf(qv[e], pv[e], av[e]);
            g1_b[n][kk] = vh.v;
        }
    }

    // ---- main loop: 13 tiles of 16 t-rows, fully unrolled, ZERO barriers ----
    float O0 = 0.f, O1 = 0.f, O2 = 0.f, O3 = 0.f, den = 0.f;
    #pragma unroll
    for (int ti = 0; ti < NT2; ++ti) {
        const int t0 = ti * 16;
        const int buf = ti & 1;

        // convert current k tile to B-frags
        bf16x8 kf0, kf1;
        {
            BF8u u;
            u.b[0]=(__bf16)pf0.x; u.b[1]=(__bf16)pf0.y; u.b[2]=(__bf16)pf0.z; u.b[3]=(__bf16)pf0.w;
            u.b[4]=(__bf16)pf1.x; u.b[5]=(__bf16)pf1.y; u.b[6]=(__bf16)pf1.z; u.b[7]=(__bf16)pf1.w;
            kf0 = u.v;
            u.b[0]=(__bf16)pf2.x; u.b[1]=(__bf16)pf2.y; u.b[2]=(__bf16)pf2.z; u.b[3]=(__bf16)pf2.w;
            u.b[4]=(__bf16)pf3.x; u.b[5]=(__bf16)pf3.y; u.b[6]=(__bf16)pf3.z; u.b[7]=(__bf16)pf3.w;
            kf1 = u.v;
        }
        // issue next k tile (lands under this tile's compute)
        if (ti + 1 < NT2) {
            int t = t0 + 16 + jn;
            t = t < NT ? t : NT - 1;
            const float* p = kb + (size_t)t * ND + g8;
            pf0 = *(const float4*)(p);
            pf1 = *(const float4*)(p + 4);
            pf2 = *(const float4*)(p + 32);
            pf3 = *(const float4*)(p + 36);
        }

        // GEMM1: h1^T(ti) = B_b^T @ k^T  -> relu(+qh) -> H1[buf]
        #pragma unroll
        for (int n = 0; n < 8; ++n) {
            f32x4 ac = {0.f, 0.f, 0.f, 0.f};
            ac = MFMA16(g1_b[n][0], kf0, ac);
            ac = MFMA16(g1_b[n][1], kf1, ac);
            const float4 qv = *(const float4*)(QH + 16 * n + 4 * g4);
            BF4u pk;
            pk.b[0] = (__bf16)fmaxf(ac[0] + qv.x, 0.f);
            pk.b[1] = (__bf16)fmaxf(ac[1] + qv.y, 0.f);
            pk.b[2] = (__bf16)fmaxf(ac[2] + qv.z, 0.f);
            pk.b[3] = (__bf16)fmaxf(ac[3] + qv.w, 0.f);
            *(uint2*)(&H1[buf][jn][16 * n + 4 * g4]) = pk.u2;
        }

        // GEMM2: C2[h2][t] = W2^T @ h1  (h1 B-frags from wave-private LDS)
        bf16x8 hf[4];
        #pragma unroll
        for (int kk = 0; kk < 4; ++kk)
            hf[kk] = *(const bf16x8*)(&H1[buf][jn][32 * kk + g8]);
        f32x4 a2[4];
        #pragma unroll
        for (int ht = 0; ht < 4; ++ht) {
            f32x4 ac = {0.f, 0.f, 0.f, 0.f};
            ac = MFMA16(w2f[ht][0], hf[0], ac);
            ac = MFMA16(w2f[ht][1], hf[1], ac);
            ac = MFMA16(w2f[ht][2], hf[2], ac);
            ac = MFMA16(w2f[ht][3], hf[3], ac);
            a2[ht] = ac;
        }

        // score s[t=jn] = sum_h2 relu(C2 + b2) * Wo ; reduce over g4-lanes
        float sp = 0.f;
        #pragma unroll
        for (int ht = 0; ht < 4; ++ht) {
            const float4 bv = *(const float4*)(B2WO + 16 * ht + 4 * g4);
            const float4 wv = *(const float4*)(B2WO + 64 + 16 * ht + 4 * g4);
            sp += fmaxf(a2[ht][0] + bv.x, 0.f) * wv.x;
            sp += fmaxf(a2[ht][1] + bv.y, 0.f) * wv.y;
            sp += fmaxf(a2[ht][2] + bv.z, 0.f) * wv.z;
            sp += fmaxf(a2[ht][3] + bv.w, 0.f) * wv.w;
        }
        sp += __shfl_xor(sp, 16);
        sp += __shfl_xor(sp, 32);

        const int t = t0 + jn;
        const int mkv = mask[(size_t)b * NT + (t < NT ? t : NT - 1)];
        const float e = (t < NT && mkv != 0) ? __expf(sp) : 0.f;
        den += e;
        if (lane < 16) EB[buf][jn] = e;

        // V accumulate: lane (jn,g4) owns d = 4*jn..+4, t-rows t0 + 4*g4 + u
        #pragma unroll
        for (int u = 0; u < 4; ++u) {
            const float ev = EB[buf][4 * g4 + u];
            int tv = t0 + 4 * g4 + u;
            tv = tv < NT ? tv : NT - 1;
            const float4 vv = *(const float4*)(vb + (size_t)tv * ND + 4 * jn);
            O0 = fmaf(ev, vv.x, O0);
            O1 = fmaf(ev, vv.y, O1);
            O2 = fmaf(ev, vv.z, O2);
            O3 = fmaf(ev, vv.w, O3);
        }
    }

    // ---- final reduces (wave-local) + store ----
    O0 += __shfl_xor(O0, 16); O0 += __shfl_xor(O0, 32);
    O1 += __shfl_xor(O1, 16); O1 += __shfl_xor(O1, 32);
    O2 += __shfl_xor(O2, 16); O2 += __shfl_xor(O2, 32);
    O3 += __shfl_xor(O3, 16); O3 += __shfl_xor(O3, 32);
    den += __shfl_xor(den, 1);
    den += __shfl_xor(den, 2);
    den += __shfl_xor(den, 4);
    den += __shfl_xor(den, 8);
    if (lane < 16) {
        const float inv = 1.f / den;
        float4 o{O0 * inv, O1 * inv, O2 * inv, O3 * inv};
        *(float4*)(out + (size_t)b * ND + 4 * jn) = o;
    }
}

extern "C" void kernel_launch(void* const* d_in, const int* in_sizes, int n_in,
                              void* d_out, int out_size, void* d_ws, size_t ws_size,
                              hipStream_t stream) {
    const float* query = (const float*)d_in[0];
    const float* key   = (const float*)d_in[1];
    const float* value = (const float*)d_in[2];
    const int*   maskp = (const int*)d_in[3];
    const float* W1    = (const float*)d_in[4];
    const float* b1    = (const float*)d_in[5];
    const float* W2    = (const float*)d_in[6];
    const float* b2    = (const float*)d_in[7];
    const float* Wo    = (const float*)d_in[8];
    float* out = (float*)d_out;

    float* QpT = (float*)d_ws;                 // 128*64 f32
    float* AbT = QpT + NH1 * ND;               // 128*64 f32
    float* PT  = AbT + NH1 * ND;               // 128*64 f32
    __bf16* W2t = (__bf16*)(PT + NH1 * ND);    // 64*128 bf16

    prep_kernel<<<32, 256, 0, stream>>>(W1, W2, QpT, AbT, PT, W2t);
    attn_main<<<NB, 64, 0, stream>>>(query, key, value, maskp, b1, b2, Wo,
                                     QpT, AbT, PT, W2t, out);
}